// Round 1
// baseline (422.786 us; speedup 1.0000x reference)
//
#include <hip/hip_runtime.h>
#include <stdint.h>

// Problem constants (from reference setup_inputs): B,H,T,S,D
#define B_ 2
#define H_ 16
#define T_ 2048
#define S_ 2048
#define D_ 128

typedef float  f32x4  __attribute__((ext_vector_type(4)));
typedef short  bf16x8 __attribute__((ext_vector_type(8)));

// ---------------------------------------------------------------------------
// e4m3fn fake-quant to GRID value (no scale applied): y = RNE_e4m3(clip(x*inv, +-448))
// Grid values are exactly representable in bf16 (3-bit mantissa subset).
__device__ __forceinline__ float qdq_grid(float x, float inv_scale) {
  float y = x * inv_scale;
  y = fminf(fmaxf(y, -448.0f), 448.0f);
  uint32_t u    = __float_as_uint(y);
  uint32_t sign = u & 0x80000000u;
  uint32_t mag  = u & 0x7fffffffu;
  if (mag < 0x3c800000u) {           // |y| < 2^-6 : e4m3 subnormal range, grid 2^-9
    float r = rintf(__uint_as_float(mag) * 512.0f) * 0.001953125f;  // RNE (v_rndne)
    return __uint_as_float(__float_as_uint(r) | sign);
  }
  uint32_t lsb = (mag >> 20) & 1u;   // round mantissa to 3 bits, RNE w/ carry
  mag += 0x7ffffu + lsb;
  mag &= 0xfff00000u;
  return __uint_as_float(mag | sign);
}

__device__ __forceinline__ ushort f32_to_bf16_bits(float f) {
  return (ushort)(__float_as_uint(f) >> 16);   // exact for e4m3 grid values
}

// ---------------------------------------------------------------------------
// Kernel 1: abs-max reduction (uint-bit atomicMax; valid since values >= 0)
__global__ void amax_kernel(const float* __restrict__ x, long n4,
                            unsigned* __restrict__ out) {
  const f32x4* x4 = (const f32x4*)x;
  long i      = (long)blockIdx.x * blockDim.x + threadIdx.x;
  long stride = (long)gridDim.x * blockDim.x;
  float m = 0.0f;
  for (; i < n4; i += stride) {
    f32x4 v = x4[i];
    m = fmaxf(m, fmaxf(fmaxf(fabsf(v[0]), fabsf(v[1])),
                       fmaxf(fabsf(v[2]), fabsf(v[3]))));
  }
  #pragma unroll
  for (int off = 32; off; off >>= 1) m = fmaxf(m, __shfl_xor(m, off, 64));
  if ((threadIdx.x & 63) == 0) atomicMax(out, __float_as_uint(m));
}

// ---------------------------------------------------------------------------
// Kernel 2: quantize v to e4m3 grid values (bf16) + transpose -> Vt[bh][d][s]
// grid: 32 bh * 64 s-chunks; block 256 = 128 d * 2 halves * 16 s each
__global__ void quantv_kernel(const float* __restrict__ v,
                              ushort* __restrict__ vt,
                              const unsigned* __restrict__ amax_bits) {
  float amax = __uint_as_float(amax_bits[1]);
  float inv  = 448.0f / fmaxf(amax, 1e-12f);
  int bid = blockIdx.x;
  int bh  = bid >> 6;
  int s0  = (bid & 63) * 32;
  int d   = threadIdx.x & 127;
  int h2  = threadIdx.x >> 7;          // 0,1
  const float* vb  = v  + (size_t)bh * S_ * D_;
  ushort*      vtb = vt + (size_t)bh * D_ * S_;
  ushort tmp[16];
  #pragma unroll
  for (int i = 0; i < 16; ++i) {
    float x = vb[(size_t)(s0 + h2 * 16 + i) * D_ + d];
    tmp[i] = f32_to_bf16_bits(qdq_grid(x, inv));
  }
  ushort* dst = vtb + (size_t)d * S_ + s0 + h2 * 16;   // 32 B contiguous, aligned
  #pragma unroll
  for (int i = 0; i < 2; ++i) {
    ((uint4*)dst)[i] = ((uint4*)tmp)[i];
  }
}

// ---------------------------------------------------------------------------
// Kernel 3: GEMM  C[t,d] = (sum_s Aq[t,s] * Vq[s,d]) * scale_a*scale_v
// 512 blocks: (bh, t-tile of 128). 4 waves stacked vertically (32 rows each),
// full D=128 width. No LDS, no barriers: A f32 direct from global with
// in-register quant; B = 16-B contiguous loads from Vt (L2-resident).
template <bool USE_VT>
__global__ __launch_bounds__(256, 2)
void gemm_kernel(const float* __restrict__ A, const ushort* __restrict__ Vt,
                 const float* __restrict__ Vf, float* __restrict__ out,
                 const unsigned* __restrict__ amax_bits) {
  float amax_a  = fmaxf(__uint_as_float(amax_bits[0]), 1e-12f);
  float amax_v  = fmaxf(__uint_as_float(amax_bits[1]), 1e-12f);
  float scale_a = amax_a / 448.0f;
  float scale_v = amax_v / 448.0f;
  float inv_a   = 448.0f / amax_a;
  float inv_v   = 448.0f / amax_v;
  float out_scale = scale_a * scale_v;

  int bid  = blockIdx.x;
  int bh   = bid >> 4;                 // 0..31
  int t0   = (bid & 15) * 128;
  int b    = bh >> 4;                  // H_=16
  int h    = bh & 15;

  int wave = threadIdx.x >> 6;         // 0..3 -> rows [t0+32w, +32)
  int lane = threadIdx.x & 63;
  int lr   = lane & 15;                // A row-in-frag / B col / C col
  int kg   = lane >> 4;                // k-group (k = kg*8 + j)

  const float*  Ab  = A + (size_t)bh * T_ * S_ + (size_t)(t0 + wave * 32) * S_;
  const float*  a0  = Ab + (size_t)lr * S_;         // mi=0 row
  const float*  a1  = Ab + (size_t)(16 + lr) * S_;  // mi=1 row
  const ushort* vrow = Vt + (size_t)bh * D_ * S_ + (size_t)lr * S_;
  const float*  vfb  = Vf + (size_t)bh * S_ * D_;

  f32x4 acc[2][8];
  #pragma unroll
  for (int i = 0; i < 2; ++i)
    #pragma unroll
    for (int j = 0; j < 8; ++j) acc[i][j] = (f32x4)0.0f;

  for (int ks = 0; ks < S_ / 32; ++ks) {
    int kb = ks * 32 + kg * 8;

    // ---- B fragments: lane holds Vq[kb..kb+7][d = ni*16+lr]
    bf16x8 bf[8];
    if (USE_VT) {
      #pragma unroll
      for (int ni = 0; ni < 8; ++ni)
        bf[ni] = *(const bf16x8*)(vrow + (size_t)ni * 16 * S_ + kb);
    } else {
      #pragma unroll
      for (int ni = 0; ni < 8; ++ni) {
        bf16x8 f;
        #pragma unroll
        for (int j = 0; j < 8; ++j) {
          float x = vfb[(size_t)(kb + j) * D_ + ni * 16 + lr];
          f[j] = (short)f32_to_bf16_bits(qdq_grid(x, inv_v));
        }
        bf[ni] = f;
      }
    }

    // ---- A fragments: lane holds Aq[row][kb..kb+7], quantized in-register
    bf16x8 af[2];
    #pragma unroll
    for (int mi = 0; mi < 2; ++mi) {
      const float* ap = (mi ? a1 : a0) + kb;
      f32x4 x0 = *(const f32x4*)(ap);
      f32x4 x1 = *(const f32x4*)(ap + 4);
      bf16x8 f;
      #pragma unroll
      for (int j = 0; j < 4; ++j) {
        f[j]     = (short)f32_to_bf16_bits(qdq_grid(x0[j], inv_a));
        f[j + 4] = (short)f32_to_bf16_bits(qdq_grid(x1[j], inv_a));
      }
      af[mi] = f;
    }

    #pragma unroll
    for (int mi = 0; mi < 2; ++mi)
      #pragma unroll
      for (int ni = 0; ni < 8; ++ni)
        acc[mi][ni] = __builtin_amdgcn_mfma_f32_16x16x32_bf16(
            af[mi], bf[ni], acc[mi][ni], 0, 0, 0);
  }

  // ---- epilogue: C/D layout col=lane&15, row=(lane>>4)*4+r  [guide §3, m89]
  // out[b][t][h][d], d = ni*16+lr, t = t0 + wave*32 + mi*16 + kg*4 + r
  float* ob = out + (size_t)b * T_ * H_ * D_ + (size_t)h * D_;
  int trow = t0 + wave * 32;
  #pragma unroll
  for (int mi = 0; mi < 2; ++mi)
    #pragma unroll
    for (int ni = 0; ni < 8; ++ni) {
      int d = ni * 16 + lr;
      #pragma unroll
      for (int r = 0; r < 4; ++r) {
        int t = trow + mi * 16 + kg * 4 + r;
        ob[(size_t)t * H_ * D_ + d] = acc[mi][ni][r] * out_scale;
      }
    }
}

// ---------------------------------------------------------------------------
extern "C" void kernel_launch(void* const* d_in, const int* in_sizes, int n_in,
                              void* d_out, int out_size, void* d_ws, size_t ws_size,
                              hipStream_t stream) {
  const float* aw = (const float*)d_in[0];
  const float* v  = (const float*)d_in[1];
  float* out      = (float*)d_out;

  unsigned* amax_bits = (unsigned*)d_ws;
  ushort*   vt        = (ushort*)((char*)d_ws + 256);
  size_t vt_need = 256 + (size_t)B_ * H_ * D_ * S_ * sizeof(ushort);

  hipMemsetAsync(d_ws, 0, 16, stream);

  long n4a = (long)B_ * H_ * T_ * S_ / 4;
  long n4v = (long)B_ * H_ * S_ * D_ / 4;
  amax_kernel<<<2048, 256, 0, stream>>>(aw, n4a, amax_bits + 0);
  amax_kernel<<<256,  256, 0, stream>>>(v,  n4v, amax_bits + 1);

  if (ws_size >= vt_need) {
    quantv_kernel<<<32 * 64, 256, 0, stream>>>(v, vt, amax_bits);
    gemm_kernel<true><<<B_ * H_ * (T_ / 128), 256, 0, stream>>>(
        aw, vt, v, out, amax_bits);
  } else {
    gemm_kernel<false><<<B_ * H_ * (T_ / 128), 256, 0, stream>>>(
        aw, vt, v, out, amax_bits);
  }
}